// Round 8
// baseline (343.689 us; speedup 1.0000x reference)
//
#include <hip/hip_runtime.h>
#include <hip/hip_bf16.h>

// Single-head causal attention. B=512, T=256, C=384 (n_embd), H=64.
// scale = C^-0.5 (reference scales by n_embd, NOT head_size).
// De-fused: lean QKV GEMM (direct x loads, weight LDS dbuf, 3 blocks/CU)
// writes fragment-order qf/kf/vf to workspace; attention runs as a separate
// 2048-block kernel at 8 blocks/CU (32 waves/CU) with zero barriers --
// the wave-parallelism the serial softmax chain needs.

#define Bsz 512
#define Tt  256
#define Cc  384
#define Hh  64

typedef __attribute__((ext_vector_type(8))) short bf16x8;
typedef __attribute__((ext_vector_type(4))) float f32x4;

__device__ __forceinline__ unsigned short f2bf(float f) {
    unsigned int u = __float_as_uint(f);
    unsigned int r = (u + 0x7fffu + ((u >> 16) & 1u)) >> 16;   // RNE
    return (unsigned short)r;
}
__device__ __forceinline__ float bf2f(unsigned short b) {
    return __uint_as_float(((unsigned int)b) << 16);
}
__device__ __forceinline__ bf16x8 pack8v(f32x4 a, f32x4 b) {
    union { __hip_bfloat162 h2[4]; bf16x8 v; } u;
    u.h2[0] = __float22bfloat162_rn(float2{a[0], a[1]});
    u.h2[1] = __float22bfloat162_rn(float2{a[2], a[3]});
    u.h2[2] = __float22bfloat162_rn(float2{b[0], b[1]});
    u.h2[3] = __float22bfloat162_rn(float2{b[2], b[3]});
    return u.v;
}
// async 16B global->LDS (direct-to-LDS DMA; dest must be uniform base + lane*16)
__device__ __forceinline__ void gload_lds16(const void* g, void* l) {
    __builtin_amdgcn_global_load_lds(
        (const __attribute__((address_space(1))) unsigned int*)g,
        (__attribute__((address_space(3))) unsigned int*)l, 16, 0, 0);
}

// ---------------- kernel 0: weights -> B-fragment order ------------------------
// wtf element ((kc*12+nt)*64 + lane)*8 + j = Wt[n=nt*16+(lane&15)][k=kc*32+(lane>>4)*8+j]
__global__ __launch_bounds__(256) void prep_kernel(const float* __restrict__ Wq,
                                                   const float* __restrict__ Wk,
                                                   const float* __restrict__ Wv,
                                                   unsigned short* __restrict__ wtf) {
    int idx = blockIdx.x * 256 + threadIdx.x;
    if (idx >= 192 * 384) return;
    int j = idx & 7;
    int l = (idx >> 3) & 63;
    int t = idx >> 9;                 // kc*12 + nt
    int kc = t / 12, nt = t - kc * 12;
    int n = nt * 16 + (l & 15);
    int k = kc * 32 + (l >> 4) * 8 + j;
    const float* W = (n < 64) ? Wq : ((n < 128) ? Wk : Wv);
    wtf[idx] = f2bf(W[k * 64 + (n & 63)]);
}

// ---------------- kernel 1: QKV projection (lean, 3 blocks/CU) -----------------
// 4 waves (256 thr), 1024 blocks of 128 rows. Wave w: rows w*32..+32, all 12
// col-tiles (acc[2][12]). x A-frags loaded DIRECT from global (no cross-wave
// reuse -> no x-LDS); weights double-buffered in 24 KB LDS via global_load_lds
// with single-chunk lookahead (verified round-4/5 loop). 24 KB LDS + ~150 VGPR
// -> 3 blocks/CU: barrier drains of one block overlap compute of the others.
// Output fragment layouts (verified round 0):
//  qf/kf: [g=row>>4][s=d>>5][lane=((d>>3)&3)*16 + (row&15)][j=d&7]
//  vf:    [b][ks2=t>>5][ht=d>>4][lane=((t>>3)&3)*16 + (d&15)][j=t&7]
__global__ __launch_bounds__(256, 3) void qkv_kernel(const float* __restrict__ x,
                                                     const float* __restrict__ bq,
                                                     const float* __restrict__ bk,
                                                     const float* __restrict__ bv,
                                                     const unsigned short* __restrict__ wtf,
                                                     unsigned short* __restrict__ qf,
                                                     unsigned short* __restrict__ kf,
                                                     unsigned short* __restrict__ vf) {
    __shared__ unsigned short wtl[2][6144];   // 24 KB weight chunk double-buffer

    const int tid = threadIdx.x;
    const int w = tid >> 6, lane = tid & 63, quad = lane >> 4, cl = lane & 15;
    const int rb = blockIdx.x * 128;

    f32x4 acc[2][12];
#pragma unroll
    for (int rt = 0; rt < 2; ++rt)
#pragma unroll
        for (int nt = 0; nt < 12; ++nt) acc[rt][nt] = (f32x4){0.f, 0.f, 0.f, 0.f};

    // 256 threads stage 768 16B-slots: 3 DMAs per thread
#define STAGE_W(c_) {                                                                \
    const unsigned short* s_ = wtf + (size_t)(c_) * 6144;                            \
    unsigned short* d_ = &wtl[(c_) & 1][0];                                          \
    gload_lds16(s_ + tid * 8, d_ + tid * 8);                                         \
    gload_lds16(s_ + (256 + tid) * 8, d_ + (256 + tid) * 8);                         \
    gload_lds16(s_ + (512 + tid) * 8, d_ + (512 + tid) * 8); }

    const float* xp0 = x + ((size_t)rb + w * 32 + cl) * Cc + quad * 8;
    const float* xp1 = xp0 + 16 * Cc;

    f32x4 Xc0, Xc1, Xc2, Xc3, Xn0, Xn1, Xn2, Xn3;
    STAGE_W(0);
    Xc0 = *(const f32x4*)(xp0);
    Xc1 = *(const f32x4*)(xp0 + 4);
    Xc2 = *(const f32x4*)(xp1);
    Xc3 = *(const f32x4*)(xp1 + 4);

#pragma unroll 1
    for (int k = 0; k < 12; ++k) {
        __syncthreads();   // chunk-k DMA (issued last iter / prologue) visible
        if (k < 11) {
            STAGE_W(k + 1);
            Xn0 = *(const f32x4*)(xp0 + (k + 1) * 32);
            Xn1 = *(const f32x4*)(xp0 + (k + 1) * 32 + 4);
            Xn2 = *(const f32x4*)(xp1 + (k + 1) * 32);
            Xn3 = *(const f32x4*)(xp1 + (k + 1) * 32 + 4);
        }
        {
            bf16x8 a0 = pack8v(Xc0, Xc1), a1 = pack8v(Xc2, Xc3);
            const unsigned short* wb = &wtl[k & 1][0];
#pragma unroll
            for (int nt = 0; nt < 12; ++nt) {
                bf16x8 bfr = *(const bf16x8*)&wb[(nt * 64 + lane) * 8];
                acc[0][nt] = __builtin_amdgcn_mfma_f32_16x16x32_bf16(a0, bfr, acc[0][nt], 0, 0, 0);
                acc[1][nt] = __builtin_amdgcn_mfma_f32_16x16x32_bf16(a1, bfr, acc[1][nt], 0, 0, 0);
            }
        }
        Xc0 = Xn0; Xc1 = Xn1; Xc2 = Xn2; Xc3 = Xn3;
    }

    // epilogue: bias + bf16 cast, scatter into GLOBAL fragment buffers (round-0)
#pragma unroll
    for (int nt = 0; nt < 12; ++nt) {
        int col = nt * 16 + cl;
        if (col < 128) {
            float bias = (col < 64) ? bq[col] : bk[col - 64];
            unsigned short* dst = (col < 64) ? qf : kf;
            int h = col & 63;
            int sh = h >> 5, qp = (h >> 3) & 3, j = h & 7;
#pragma unroll
            for (int rt = 0; rt < 2; ++rt) {
                int m0 = rb + w * 32 + rt * 16 + quad * 4;
                size_t basei = (size_t)(m0 >> 4) * 1024 + sh * 512 + qp * 128 + quad * 32 + j;
#pragma unroll
                for (int r = 0; r < 4; ++r)
                    dst[basei + r * 8] = f2bf(acc[rt][nt][r] + bias);
            }
        } else {
            int h = col - 128;
            float bias = bv[h];
            int ht = h >> 4, clp = h & 15;
#pragma unroll
            for (int rt = 0; rt < 2; ++rt) {
                int m0 = rb + w * 32 + rt * 16 + quad * 4;
                int bI = m0 >> 8, t0 = m0 & 255;
                int ks2 = t0 >> 5, qp = (t0 >> 3) & 3, j0 = t0 & 7;
                unsigned long long pk =
                      (unsigned long long)f2bf(acc[rt][nt][0] + bias)
                    | ((unsigned long long)f2bf(acc[rt][nt][1] + bias) << 16)
                    | ((unsigned long long)f2bf(acc[rt][nt][2] + bias) << 32)
                    | ((unsigned long long)f2bf(acc[rt][nt][3] + bias) << 48);
                *(unsigned long long*)&vf[(size_t)((bI * 8 + ks2) * 4 + ht) * 512
                                          + qp * 128 + clp * 8 + j0] = pk;
            }
        }
    }
}

// ---------------- kernel 2: causal attention (zero barriers, 8 blocks/CU) ------
// Wave = 16 q-rows. Q/K/V fragments loaded contiguous-coalesced from L2.
// Only LDS: 1 KB/wave P round-trip (C-layout -> A-layout), XOR-swizzled.
// Max-free softmax (scores O(0.15)): unnormalized accumulate, divide at end.
__global__ __launch_bounds__(256) void attn_kernel(const unsigned short* __restrict__ qf,
                                                   const unsigned short* __restrict__ kf,
                                                   const unsigned short* __restrict__ vf,
                                                   float* __restrict__ out) {
    __shared__ unsigned short Pl[4 * 512];   // 4 KB: per-wave [16 rows][32 keys], swizzled

    const int tid = threadIdx.x;
    const int w = tid >> 6, lane = tid & 63, quad = lane >> 4, cl = lane & 15;
    const int b = blockIdx.y;
    const int W = blockIdx.x * 4 + w;        // 16-row q-tile index within batch (0..15)
    const int qrow0 = W * 16;
    unsigned short* P = &Pl[w * 512];
    const float SL2E = 0.07362224f;          // log2(e) / sqrt(384)

    const size_t gq = (size_t)(b * 16 + W) * 128;
    bf16x8 aq0 = *(const bf16x8*)&qf[(gq + lane) * 8];
    bf16x8 aq1 = *(const bf16x8*)&qf[(gq + 64 + lane) * 8];

    f32x4 o[4];
#pragma unroll
    for (int ht = 0; ht < 4; ++ht) o[ht] = (f32x4){0.f, 0.f, 0.f, 0.f};
    float rs[4] = {0.f, 0.f, 0.f, 0.f};

    const int nsteps = (qrow0 >> 5) + 1;     // 32-key steps covering keys 0..qrow0+15
    for (int st = 0; st < nsteps; ++st) {
#pragma unroll
        for (int half = 0; half < 2; ++half) {
            int ct = st * 2 + half;          // 16-key tile
            size_t gk = (size_t)(b * 16 + ct) * 128;
            bf16x8 b0 = *(const bf16x8*)&kf[(gk + lane) * 8];
            bf16x8 b1 = *(const bf16x8*)&kf[(gk + 64 + lane) * 8];
            f32x4 sc = (f32x4){0.f, 0.f, 0.f, 0.f};
            sc = __builtin_amdgcn_mfma_f32_16x16x32_bf16(aq0, b0, sc, 0, 0, 0);
            sc = __builtin_amdgcn_mfma_f32_16x16x32_bf16(aq1, b1, sc, 0, 0, 0);
            int key = ct * 16 + cl;
#pragma unroll
            for (int r = 0; r < 4; ++r) {
                int row = quad * 4 + r;
                float p = (key <= qrow0 + row) ? exp2f(sc[r] * SL2E) : 0.f;
                unsigned short pb = f2bf(p);
                rs[r] += bf2f(pb);
                int k32 = half * 16 + cl;
                int chunk = (k32 >> 3) ^ quad;           // XOR swizzle (row>>2 == quad)
                P[row * 32 + chunk * 8 + (k32 & 7)] = pb;
            }
        }
        // prefetch V fragments (overlaps LDS drain)
        bf16x8 bvf[4];
#pragma unroll
        for (int ht = 0; ht < 4; ++ht)
            bvf[ht] = *(const bf16x8*)&vf[((size_t)((b * 8 + st) * 4 + ht) * 64 + lane) * 8];

        asm volatile("s_waitcnt lgkmcnt(0)" ::: "memory");   // wave-local P drain
        bf16x8 ap = *(const bf16x8*)((const char*)P + cl * 64 + ((quad ^ (cl >> 2)) & 3) * 16);
#pragma unroll
        for (int ht = 0; ht < 4; ++ht)
            o[ht] = __builtin_amdgcn_mfma_f32_16x16x32_bf16(ap, bvf[ht], o[ht], 0, 0, 0);
    }

    // normalize by row-sum (sum over the 16 key-lanes of each quad) and store
#pragma unroll
    for (int r = 0; r < 4; ++r) {
        float s = rs[r];
        s += __shfl_xor(s, 1);
        s += __shfl_xor(s, 2);
        s += __shfl_xor(s, 4);
        s += __shfl_xor(s, 8);
        float inv = 1.0f / s;
        int t = qrow0 + quad * 4 + r;
#pragma unroll
        for (int ht = 0; ht < 4; ++ht)
            out[((size_t)(b * Tt + t)) * Hh + ht * 16 + cl] = o[ht][r] * inv;
    }
}

// ---------------- launcher ----------------------------------------------------
extern "C" void kernel_launch(void* const* d_in, const int* in_sizes, int n_in,
                              void* d_out, int out_size, void* d_ws, size_t ws_size,
                              hipStream_t stream) {
    const float* x  = (const float*)d_in[0];
    const float* Wq = (const float*)d_in[1];
    const float* bq = (const float*)d_in[2];
    const float* Wk = (const float*)d_in[3];
    const float* bk = (const float*)d_in[4];
    const float* Wv = (const float*)d_in[5];
    const float* bv = (const float*)d_in[6];
    float* out = (float*)d_out;

    char* ws = (char*)d_ws;
    unsigned short* wtf = (unsigned short*)(ws);                       // 144 KB frag-order W
    unsigned short* qf  = (unsigned short*)(ws + (size_t)(1  << 20));  // 16 MiB
    unsigned short* kf  = (unsigned short*)(ws + (size_t)(17 << 20));  // 16 MiB
    unsigned short* vf  = (unsigned short*)(ws + (size_t)(33 << 20));  // 16 MiB

    prep_kernel<<<288, 256, 0, stream>>>(Wq, Wk, Wv, wtf);
    qkv_kernel<<<1024, 256, 0, stream>>>(x, bq, bk, bv, wtf, qf, kf, vf);
    attn_kernel<<<dim3(4, Bsz), 256, 0, stream>>>(qf, kf, vf, out);
}